// Round 4
// baseline (20615.750 us; speedup 1.0000x reference)
//
#include <hip/hip_runtime.h>
#include <hip/hip_bf16.h>
#include <math.h>

#define NN 4096
#define DIN 2048
#define HID 256
#define NHEADS 4
#define CAP 1024       // fast-path nnz per row (30-NN + in-degree; hubs can be large)
#define OVF_CAP 131072 // spill capacity for rows exceeding CAP (exactness guarantee)
#define PW 128         // spmm panel width (floats): 4096*PW*4B = 2MB panel -> L2-resident

// ---------------------------------------------------------------------------
// Projection GEMM (NT) for ONE head: out[n][c] = sum_d X[n][d]*W[c][d] + b[c]
// ---------------------------------------------------------------------------
__global__ __launch_bounds__(256) void proj_kernel(
    const float* __restrict__ X, const float* __restrict__ Wq, const float* __restrict__ bq,
    const float* __restrict__ Wk, const float* __restrict__ bk,
    float* __restrict__ qbuf, float* __restrict__ kbuf, int h)
{
    const int isK = blockIdx.z;
    const float* W    = (isK ? Wk : Wq) + (size_t)h * HID * DIN;
    const float* bias = (isK ? bk : bq) + h * HID;
    float* out = isK ? kbuf : qbuf;

    const int bm = blockIdx.x * 64;
    const int bn = blockIdx.y * 64;
    const int t  = threadIdx.x;
    const int tx = t & 15, ty = t >> 4;
    const int lr = t >> 2, lk = (t & 3) * 4;

    __shared__ float As[16][68];
    __shared__ float Bs[16][68];
    float acc[4][4] = {};

    for (int k0 = 0; k0 < DIN; k0 += 16) {
        float4 av = *(const float4*)(X + (size_t)(bm + lr) * DIN + k0 + lk);
        float4 bv = *(const float4*)(W + (size_t)(bn + lr) * DIN + k0 + lk);
        As[lk+0][lr]=av.x; As[lk+1][lr]=av.y; As[lk+2][lr]=av.z; As[lk+3][lr]=av.w;
        Bs[lk+0][lr]=bv.x; Bs[lk+1][lr]=bv.y; Bs[lk+2][lr]=bv.z; Bs[lk+3][lr]=bv.w;
        __syncthreads();
        #pragma unroll
        for (int kk = 0; kk < 16; ++kk) {
            const float4 a4 = *(const float4*)&As[kk][ty*4];
            const float4 b4 = *(const float4*)&Bs[kk][tx*4];
            const float a[4] = {a4.x,a4.y,a4.z,a4.w};
            const float b[4] = {b4.x,b4.y,b4.z,b4.w};
            #pragma unroll
            for (int i = 0; i < 4; ++i)
                #pragma unroll
                for (int j = 0; j < 4; ++j)
                    acc[i][j] = fmaf(a[i], b[j], acc[i][j]);
        }
        __syncthreads();
    }
    #pragma unroll
    for (int i = 0; i < 4; ++i) {
        const int m = bm + ty*4 + i;
        float4 o;
        o.x = acc[i][0] + bias[bn+tx*4+0];
        o.y = acc[i][1] + bias[bn+tx*4+1];
        o.z = acc[i][2] + bias[bn+tx*4+2];
        o.w = acc[i][3] + bias[bn+tx*4+3];
        *(float4*)(out + (size_t)m * HID + bn + tx*4) = o;
    }
}

// ---------------------------------------------------------------------------
__global__ __launch_bounds__(64) void rownorm_kernel(
    const float* __restrict__ q, const float* __restrict__ k,
    float* __restrict__ sqq, float* __restrict__ sqk)
{
    const int row = blockIdx.x;
    const int lane = threadIdx.x;
    const float* src = (blockIdx.y ? k : q) + (size_t)row * HID;
    float4 v = *(const float4*)(src + lane * 4);
    float s = v.x*v.x + v.y*v.y + v.z*v.z + v.w*v.w;
    for (int off = 32; off; off >>= 1) s += __shfl_down(s, off);
    if (lane == 0) (blockIdx.y ? sqk : sqq)[row] = s;
}

// ---------------------------------------------------------------------------
// Gram GEMM (NT, K=HID) + distance epilogue.
// ---------------------------------------------------------------------------
__global__ __launch_bounds__(256) void dist_kernel(
    const float* __restrict__ q, const float* __restrict__ k,
    const float* __restrict__ sqq, const float* __restrict__ sqk,
    float* __restrict__ Dm)
{
    const int bm = blockIdx.x * 64;
    const int bn = blockIdx.y * 64;
    const int t  = threadIdx.x;
    const int tx = t & 15, ty = t >> 4;
    const int lr = t >> 2, lk = (t & 3) * 4;

    __shared__ float As[16][68];
    __shared__ float Bs[16][68];
    float acc[4][4] = {};

    for (int k0 = 0; k0 < HID; k0 += 16) {
        float4 av = *(const float4*)(q + (size_t)(bm + lr) * HID + k0 + lk);
        float4 bv = *(const float4*)(k + (size_t)(bn + lr) * HID + k0 + lk);
        As[lk+0][lr]=av.x; As[lk+1][lr]=av.y; As[lk+2][lr]=av.z; As[lk+3][lr]=av.w;
        Bs[lk+0][lr]=bv.x; Bs[lk+1][lr]=bv.y; Bs[lk+2][lr]=bv.z; Bs[lk+3][lr]=bv.w;
        __syncthreads();
        #pragma unroll
        for (int kk = 0; kk < 16; ++kk) {
            const float4 a4 = *(const float4*)&As[kk][ty*4];
            const float4 b4 = *(const float4*)&Bs[kk][tx*4];
            const float a[4] = {a4.x,a4.y,a4.z,a4.w};
            const float b[4] = {b4.x,b4.y,b4.z,b4.w};
            #pragma unroll
            for (int i = 0; i < 4; ++i)
                #pragma unroll
                for (int j = 0; j < 4; ++j)
                    acc[i][j] = fmaf(a[i], b[j], acc[i][j]);
        }
        __syncthreads();
    }
    #pragma unroll
    for (int i = 0; i < 4; ++i) {
        const int m = bm + ty*4 + i;
        const float sm = sqq[m];
        float4 o;
        float v0 = sm + sqk[bn+tx*4+0] - 2.0f*acc[i][0];
        float v1 = sm + sqk[bn+tx*4+1] - 2.0f*acc[i][1];
        float v2 = sm + sqk[bn+tx*4+2] - 2.0f*acc[i][2];
        float v3 = sm + sqk[bn+tx*4+3] - 2.0f*acc[i][3];
        o.x = sqrtf(fmaxf(v0, 0.0f) + 1e-10f);
        o.y = sqrtf(fmaxf(v1, 0.0f) + 1e-10f);
        o.z = sqrtf(fmaxf(v2, 0.0f) + 1e-10f);
        o.w = sqrtf(fmaxf(v3, 0.0f) + 1e-10f);
        *(float4*)(Dm + (size_t)m * NN + bn + tx*4) = o;
    }
}

// ---------------------------------------------------------------------------
// Per-row order stats via radix bisection on float bits.
// ---------------------------------------------------------------------------
__device__ unsigned radix_kth_smallest(const unsigned* s, int lane, int K)
{
    unsigned lo = 0u, hi = 0xFFFFFFFFu;
    while (lo < hi) {
        unsigned mid = lo + ((hi - lo) >> 1);
        int c = 0;
        #pragma unroll 8
        for (int i = 0; i < 64; ++i) c += (s[i*64 + lane] <= mid) ? 1 : 0;
        for (int off = 32; off; off >>= 1) c += __shfl_xor(c, off);
        if (c >= K) hi = mid; else lo = mid + 1;
    }
    return lo;
}

__global__ __launch_bounds__(64) void select_kernel(
    const float* __restrict__ Dm, float* __restrict__ mdp, float* __restrict__ kth)
{
    __shared__ unsigned s[NN];
    const int row = blockIdx.x;
    const int lane = threadIdx.x;
    const float* src = Dm + (size_t)row * NN;
    for (int c = 0; c < 16; ++c) {
        const int base = c*256 + lane*4;
        float4 v = *(const float4*)(src + base);
        s[base+0] = __float_as_uint(v.x);
        s[base+1] = __float_as_uint(v.y);
        s[base+2] = __float_as_uint(v.z);
        s[base+3] = __float_as_uint(v.w);
    }
    __syncthreads();
    unsigned v11 = radix_kth_smallest(s, lane, 11);  // sort(d)[10]
    unsigned v30 = radix_kth_smallest(s, lane, 30);  // sort(d)[29]
    if (lane == 0) {
        float md = __uint_as_float(v11) + 1e-10f;
        float t  = __uint_as_float(v30) / md;
        mdp[row] = md;
        kth[row] = expf(-(t*t));   // same expr as aff_kernel -> identical rounding
    }
}

// ---------------------------------------------------------------------------
// Affinity transform in place + prune + diagonal (after prune, as reference).
// ---------------------------------------------------------------------------
__global__ __launch_bounds__(256) void aff_kernel(
    float* __restrict__ Dm, const float* __restrict__ mdp, const float* __restrict__ kthv)
{
    const size_t idx4 = ((size_t)blockIdx.x * 256 + threadIdx.x) * 4;
    const int i = (int)(idx4 >> 12);
    const int j = (int)(idx4 & 4095);
    const float m = mdp[i];
    const float kt = kthv[i];
    float4 v = *(float4*)(Dm + idx4);
    float t0 = v.x / m, t1 = v.y / m, t2 = v.z / m, t3 = v.w / m;
    float a0 = expf(-(t0*t0)), a1 = expf(-(t1*t1)), a2 = expf(-(t2*t2)), a3 = expf(-(t3*t3));
    a0 = (a0 >= kt) ? a0 : 0.0f;
    a1 = (a1 >= kt) ? a1 : 0.0f;
    a2 = (a2 >= kt) ? a2 : 0.0f;
    a3 = (a3 >= kt) ? a3 : 0.0f;
    if (j+0 == i) a0 = 1.0f;
    if (j+1 == i) a1 = 1.0f;
    if (j+2 == i) a2 = 1.0f;
    if (j+3 == i) a3 = 1.0f;
    v.x = a0; v.y = a1; v.z = a2; v.w = a3;
    *(float4*)(Dm + idx4) = v;
}

// ---------------------------------------------------------------------------
// In-place symmetrize A := A + A^T via 64x64 tile pairs.
// ---------------------------------------------------------------------------
__global__ __launch_bounds__(256) void sym_kernel(float* __restrict__ Dm)
{
    int rem = blockIdx.x;
    int bi = 0;
    while (rem >= 64 - bi) { rem -= 64 - bi; ++bi; }
    const int bj = bi + rem;

    __shared__ float T1[64][65];
    __shared__ float T2[64][65];
    const int t = threadIdx.x;
    const int lr = t >> 4;
    const int lc4 = (t & 15) * 4;

    #pragma unroll
    for (int rr = 0; rr < 4; ++rr) {
        const int r = rr*16 + lr;
        float4 v1 = *(const float4*)(Dm + (size_t)(bi*64 + r) * NN + bj*64 + lc4);
        T1[r][lc4+0]=v1.x; T1[r][lc4+1]=v1.y; T1[r][lc4+2]=v1.z; T1[r][lc4+3]=v1.w;
        float4 v2 = *(const float4*)(Dm + (size_t)(bj*64 + r) * NN + bi*64 + lc4);
        T2[r][lc4+0]=v2.x; T2[r][lc4+1]=v2.y; T2[r][lc4+2]=v2.z; T2[r][lc4+3]=v2.w;
    }
    __syncthreads();
    #pragma unroll
    for (int rr = 0; rr < 4; ++rr) {
        const int r = rr*16 + lr;
        float4 o1;
        o1.x = T1[r][lc4+0] + T2[lc4+0][r];
        o1.y = T1[r][lc4+1] + T2[lc4+1][r];
        o1.z = T1[r][lc4+2] + T2[lc4+2][r];
        o1.w = T1[r][lc4+3] + T2[lc4+3][r];
        *(float4*)(Dm + (size_t)(bi*64 + r) * NN + bj*64 + lc4) = o1;
        if (bi != bj) {
            float4 o2;
            o2.x = T2[r][lc4+0] + T1[lc4+0][r];
            o2.y = T2[r][lc4+1] + T1[lc4+1][r];
            o2.z = T2[r][lc4+2] + T1[lc4+2][r];
            o2.w = T2[r][lc4+3] + T1[lc4+3][r];
            *(float4*)(Dm + (size_t)(bj*64 + r) * NN + bi*64 + lc4) = o2;
        }
    }
}

// ---------------------------------------------------------------------------
__global__ __launch_bounds__(64) void zero_ovf_kernel(int* __restrict__ ovf_cnt)
{
    if (threadIdx.x == 0) *ovf_cnt = 0;
}

// ---------------------------------------------------------------------------
// Softmax row stats + sparse extraction. P[i][j] = ci + v_ij (v=0 off-support).
// Entries beyond CAP spill to a global overflow list -> exact for any nnz.
// ---------------------------------------------------------------------------
__global__ __launch_bounds__(256) void stats_extract_kernel(
    const float* __restrict__ A, float* __restrict__ cvec, int* __restrict__ nnz,
    int* __restrict__ cols, float* __restrict__ vals,
    int* __restrict__ ovf_cnt, int* __restrict__ ovf_row,
    int* __restrict__ ovf_col, float* __restrict__ ovf_val)
{
    __shared__ float srow[NN];
    __shared__ float red[8];
    __shared__ int cnt;
    const int row = blockIdx.x, t = threadIdx.x;
    const int lane = t & 63, wid = t >> 6;
    const float* src = A + (size_t)row * NN;

    float mx = -1e30f;
    #pragma unroll
    for (int c = 0; c < 4; ++c) {
        const int base = c*1024 + t*4;
        float4 v = *(const float4*)(src + base);
        *(float4*)&srow[base] = v;
        mx = fmaxf(mx, fmaxf(fmaxf(v.x, v.y), fmaxf(v.z, v.w)));
    }
    for (int off = 32; off; off >>= 1) mx = fmaxf(mx, __shfl_xor(mx, off));
    if (lane == 0) red[wid] = mx;
    __syncthreads();
    mx = fmaxf(fmaxf(red[0], red[1]), fmaxf(red[2], red[3]));

    float sum = 0.0f;
    #pragma unroll
    for (int c = 0; c < 4; ++c) {
        const int base = c*1024 + t*4;
        float4 v = *(float4*)&srow[base];
        sum += expf(v.x-mx) + expf(v.y-mx) + expf(v.z-mx) + expf(v.w-mx);
    }
    for (int off = 32; off; off >>= 1) sum += __shfl_xor(sum, off);
    if (lane == 0) red[4 + wid] = sum;
    if (t == 0) cnt = 0;
    __syncthreads();
    sum = red[4] + red[5] + red[6] + red[7];
    const float ci = expf(-mx) / sum;
    if (t == 0) cvec[row] = ci;

    for (int c = 0; c < 16; ++c) {
        const int j = c*256 + t;
        const float a = srow[j];
        if (a != 0.0f) {
            const float v = expf(a - mx)/sum - ci;
            int p = atomicAdd(&cnt, 1);
            if (p < CAP) {
                cols[(size_t)row*CAP + p] = j;
                vals[(size_t)row*CAP + p] = v;
            } else {
                int q = atomicAdd(ovf_cnt, 1);
                if (q < OVF_CAP) {
                    ovf_row[q] = row;
                    ovf_col[q] = j;
                    ovf_val[q] = v;
                }
            }
        }
    }
    __syncthreads();
    if (t == 0) nnz[row] = min(cnt, CAP);
}

// ---------------------------------------------------------------------------
// Column sums of Y [NN][DIN], two-stage deterministic.
// ---------------------------------------------------------------------------
__global__ __launch_bounds__(256) void colsum_partial_kernel(
    const float* __restrict__ Y, float* __restrict__ part)
{
    const int cc = blockIdx.y * 256 + threadIdx.x;
    const int r0 = blockIdx.x * 128;
    float s = 0.0f;
    for (int r = 0; r < 128; ++r) s += Y[(size_t)(r0 + r) * DIN + cc];
    part[(size_t)blockIdx.x * DIN + cc] = s;
}

__global__ __launch_bounds__(256) void colsum_final_kernel(
    const float* __restrict__ part, float* __restrict__ colsum)
{
    const int cc = blockIdx.x * 256 + threadIdx.x;
    float s = 0.0f;
    #pragma unroll
    for (int r = 0; r < 32; ++r) s += part[(size_t)r * DIN + cc];
    colsum[cc] = s;
}

// ---------------------------------------------------------------------------
// Panel-blocked sparse+rank-1 application:
//   Yout[i][panel] = c_i*colsum[panel] + sum_nz v * Y[j][panel]
// One wave per (row, panel); panel = PW floats -> gathered working set
// 4096*PW*4B = 2MB fits a 4MB XCD L2 (x-major dispatch keeps <=2 panels live).
// mode 0: write; mode 1: write 0.25x; mode 2: += 0.25x
// ---------------------------------------------------------------------------
__global__ __launch_bounds__(256) void spmm_kernel(
    const float* __restrict__ Y, const float* __restrict__ colsum,
    const float* __restrict__ cvec, const int* __restrict__ nnz,
    const int* __restrict__ cols, const float* __restrict__ vals,
    float* __restrict__ Yout, int mode)
{
    const int wave = threadIdx.x >> 6, lane = threadIdx.x & 63;
    const int row = blockIdx.x * 4 + wave;
    const int c = blockIdx.y * PW + lane * 2;

    const int n = nnz[row];
    const float ci = cvec[row];
    const int*   rc = cols + (size_t)row * CAP;
    const float* rv = vals + (size_t)row * CAP;

    const float2 s = *(const float2*)(colsum + c);
    float ax = ci * s.x, ay = ci * s.y;

    for (int e = 0; e < n; ++e) {
        const int j = rc[e];          // wave-uniform broadcast load
        const float v = rv[e];
        const float2 y = *(const float2*)(Y + (size_t)j * DIN + c);
        ax = fmaf(v, y.x, ax);
        ay = fmaf(v, y.y, ay);
    }

    float* dst = Yout + (size_t)row * DIN + c;
    float2 o;
    if (mode == 0)      { o.x = ax;            o.y = ay; }
    else if (mode == 1) { o.x = 0.25f*ax;      o.y = 0.25f*ay; }
    else {
        const float2 p = *(const float2*)dst;
        o.x = p.x + 0.25f*ax; o.y = p.y + 0.25f*ay;
    }
    *(float2*)dst = o;
}

// ---------------------------------------------------------------------------
// Apply spilled overflow entries: Yout[i][:] += scale * v * Y[j][:].
// Expected count ~0; exactness guarantee for hub rows with nnz > CAP.
// ---------------------------------------------------------------------------
__global__ __launch_bounds__(256) void spmm_fixup_kernel(
    const float* __restrict__ Y, const int* __restrict__ ovf_cnt,
    const int* __restrict__ ovf_row, const int* __restrict__ ovf_col,
    const float* __restrict__ ovf_val, float* __restrict__ Yout, float scale)
{
    const int cnt = min(*ovf_cnt, OVF_CAP);
    const int t = threadIdx.x;
    for (int e = blockIdx.x; e < cnt; e += gridDim.x) {
        const int i = ovf_row[e], j = ovf_col[e];
        const float v = ovf_val[e] * scale;
        const float* yr = Y + (size_t)j * DIN;
        float* dst = Yout + (size_t)i * DIN;
        #pragma unroll
        for (int c = t*4; c < DIN; c += 1024) {
            atomicAdd(dst + c + 0, v * yr[c + 0]);
            atomicAdd(dst + c + 1, v * yr[c + 1]);
            atomicAdd(dst + c + 2, v * yr[c + 2]);
            atomicAdd(dst + c + 3, v * yr[c + 3]);
        }
    }
}

// ---------------------------------------------------------------------------
extern "C" void kernel_launch(void* const* d_in, const int* in_sizes, int n_in,
                              void* d_out, int out_size, void* d_ws, size_t ws_size,
                              hipStream_t stream)
{
    const float* X  = (const float*)d_in[0];
    const float* Wq = (const float*)d_in[1];
    const float* bq = (const float*)d_in[2];
    const float* Wk = (const float*)d_in[3];
    const float* bk = (const float*)d_in[4];
    float* out = (float*)d_out;

    float* ws   = (float*)d_ws;
    float* qbuf = ws;                                   //  NN*HID
    float* kbuf = qbuf + (size_t)NN*HID;                //  NN*HID
    float* A    = kbuf + (size_t)NN*HID;                //  NN*NN (64MB)
    float* Y1   = A;                                    //  overlays A (A dead after extract)
    float* Y2   = A + (size_t)NN*DIN;                   //  overlays A upper half
    float* valsA= A + (size_t)NN*NN;                    //  NN*CAP
    int*   colsA= (int*)(valsA + (size_t)NN*CAP);       //  NN*CAP
    float* part = (float*)(colsA + (size_t)NN*CAP);     //  32*DIN
    float* colsum = part + 32*DIN;                      //  DIN
    float* sqq  = colsum + DIN;
    float* sqk  = sqq + NN;
    float* mdp  = sqk + NN;
    float* kth  = mdp + NN;
    float* cvec = kth + NN;
    int*   nnz  = (int*)(cvec + NN);
    int*   ovf_cnt = nnz + NN;
    int*   ovf_row = ovf_cnt + 16;
    int*   ovf_col = ovf_row + OVF_CAP;
    float* ovf_val = (float*)(ovf_col + OVF_CAP);

    for (int h = 0; h < NHEADS; ++h) {
        proj_kernel<<<dim3(NN/64, HID/64, 2), 256, 0, stream>>>(X, Wq, bq, Wk, bk, qbuf, kbuf, h);
        rownorm_kernel<<<dim3(NN, 2), 64, 0, stream>>>(qbuf, kbuf, sqq, sqk);
        dist_kernel<<<dim3(NN/64, NN/64), 256, 0, stream>>>(qbuf, kbuf, sqq, sqk, A);
        select_kernel<<<dim3(NN), 64, 0, stream>>>(A, mdp, kth);
        aff_kernel<<<dim3(NN*NN/1024), 256, 0, stream>>>(A, mdp, kth);
        sym_kernel<<<dim3(2080), 256, 0, stream>>>(A);
        zero_ovf_kernel<<<dim3(1), 64, 0, stream>>>(ovf_cnt);
        stats_extract_kernel<<<dim3(NN), 256, 0, stream>>>(A, cvec, nnz, colsA, valsA,
                                                           ovf_cnt, ovf_row, ovf_col, ovf_val);

        const float* src = X;
        for (int tpow = 1; tpow <= 6; ++tpow) {
            colsum_partial_kernel<<<dim3(32, DIN/256), 256, 0, stream>>>(src, part);
            colsum_final_kernel<<<dim3(DIN/256), 256, 0, stream>>>(part, colsum);
            float* dst;
            int mode;
            if (tpow == 6)      { dst = out; mode = (h == 0) ? 1 : 2; }
            else if (tpow & 1)  { dst = Y1;  mode = 0; }
            else                { dst = Y2;  mode = 0; }
            spmm_kernel<<<dim3(NN/4, DIN/PW), 256, 0, stream>>>(src, colsum, cvec, nnz, colsA, valsA, dst, mode);
            spmm_fixup_kernel<<<dim3(64), 256, 0, stream>>>(src, ovf_cnt, ovf_row, ovf_col, ovf_val,
                                                            dst, (tpow == 6) ? 0.25f : 1.0f);
            src = dst;
        }
    }
}

// Round 5
// 7352.716 us; speedup vs baseline: 2.8038x; 2.8038x over previous
//
#include <hip/hip_runtime.h>
#include <hip/hip_bf16.h>
#include <math.h>

#define NN 4096
#define DIN 2048
#define HID 256
#define NHEADS 4
#define CAP 1024       // fast-path nnz per row; multiple of 8 (padding invariant)
#define OVF_CAP 131072 // spill capacity for rows exceeding CAP (exactness guarantee)
#define PW 128         // spmm panel width (floats): 4096*PW*4B = 2MB panel -> L2-resident

// ---------------------------------------------------------------------------
// Projection GEMM (NT) for ONE head: out[n][c] = sum_d X[n][d]*W[c][d] + b[c]
// ---------------------------------------------------------------------------
__global__ __launch_bounds__(256) void proj_kernel(
    const float* __restrict__ X, const float* __restrict__ Wq, const float* __restrict__ bq,
    const float* __restrict__ Wk, const float* __restrict__ bk,
    float* __restrict__ qbuf, float* __restrict__ kbuf, int h)
{
    const int isK = blockIdx.z;
    const float* W    = (isK ? Wk : Wq) + (size_t)h * HID * DIN;
    const float* bias = (isK ? bk : bq) + h * HID;
    float* out = isK ? kbuf : qbuf;

    const int bm = blockIdx.x * 64;
    const int bn = blockIdx.y * 64;
    const int t  = threadIdx.x;
    const int tx = t & 15, ty = t >> 4;
    const int lr = t >> 2, lk = (t & 3) * 4;

    __shared__ float As[16][68];
    __shared__ float Bs[16][68];
    float acc[4][4] = {};

    for (int k0 = 0; k0 < DIN; k0 += 16) {
        float4 av = *(const float4*)(X + (size_t)(bm + lr) * DIN + k0 + lk);
        float4 bv = *(const float4*)(W + (size_t)(bn + lr) * DIN + k0 + lk);
        As[lk+0][lr]=av.x; As[lk+1][lr]=av.y; As[lk+2][lr]=av.z; As[lk+3][lr]=av.w;
        Bs[lk+0][lr]=bv.x; Bs[lk+1][lr]=bv.y; Bs[lk+2][lr]=bv.z; Bs[lk+3][lr]=bv.w;
        __syncthreads();
        #pragma unroll
        for (int kk = 0; kk < 16; ++kk) {
            const float4 a4 = *(const float4*)&As[kk][ty*4];
            const float4 b4 = *(const float4*)&Bs[kk][tx*4];
            const float a[4] = {a4.x,a4.y,a4.z,a4.w};
            const float b[4] = {b4.x,b4.y,b4.z,b4.w};
            #pragma unroll
            for (int i = 0; i < 4; ++i)
                #pragma unroll
                for (int j = 0; j < 4; ++j)
                    acc[i][j] = fmaf(a[i], b[j], acc[i][j]);
        }
        __syncthreads();
    }
    #pragma unroll
    for (int i = 0; i < 4; ++i) {
        const int m = bm + ty*4 + i;
        float4 o;
        o.x = acc[i][0] + bias[bn+tx*4+0];
        o.y = acc[i][1] + bias[bn+tx*4+1];
        o.z = acc[i][2] + bias[bn+tx*4+2];
        o.w = acc[i][3] + bias[bn+tx*4+3];
        *(float4*)(out + (size_t)m * HID + bn + tx*4) = o;
    }
}

// ---------------------------------------------------------------------------
__global__ __launch_bounds__(64) void rownorm_kernel(
    const float* __restrict__ q, const float* __restrict__ k,
    float* __restrict__ sqq, float* __restrict__ sqk)
{
    const int row = blockIdx.x;
    const int lane = threadIdx.x;
    const float* src = (blockIdx.y ? k : q) + (size_t)row * HID;
    float4 v = *(const float4*)(src + lane * 4);
    float s = v.x*v.x + v.y*v.y + v.z*v.z + v.w*v.w;
    for (int off = 32; off; off >>= 1) s += __shfl_down(s, off);
    if (lane == 0) (blockIdx.y ? sqk : sqq)[row] = s;
}

// ---------------------------------------------------------------------------
// Gram GEMM (NT, K=HID) + distance epilogue.
// ---------------------------------------------------------------------------
__global__ __launch_bounds__(256) void dist_kernel(
    const float* __restrict__ q, const float* __restrict__ k,
    const float* __restrict__ sqq, const float* __restrict__ sqk,
    float* __restrict__ Dm)
{
    const int bm = blockIdx.x * 64;
    const int bn = blockIdx.y * 64;
    const int t  = threadIdx.x;
    const int tx = t & 15, ty = t >> 4;
    const int lr = t >> 2, lk = (t & 3) * 4;

    __shared__ float As[16][68];
    __shared__ float Bs[16][68];
    float acc[4][4] = {};

    for (int k0 = 0; k0 < HID; k0 += 16) {
        float4 av = *(const float4*)(q + (size_t)(bm + lr) * HID + k0 + lk);
        float4 bv = *(const float4*)(k + (size_t)(bn + lr) * HID + k0 + lk);
        As[lk+0][lr]=av.x; As[lk+1][lr]=av.y; As[lk+2][lr]=av.z; As[lk+3][lr]=av.w;
        Bs[lk+0][lr]=bv.x; Bs[lk+1][lr]=bv.y; Bs[lk+2][lr]=bv.z; Bs[lk+3][lr]=bv.w;
        __syncthreads();
        #pragma unroll
        for (int kk = 0; kk < 16; ++kk) {
            const float4 a4 = *(const float4*)&As[kk][ty*4];
            const float4 b4 = *(const float4*)&Bs[kk][tx*4];
            const float a[4] = {a4.x,a4.y,a4.z,a4.w};
            const float b[4] = {b4.x,b4.y,b4.z,b4.w};
            #pragma unroll
            for (int i = 0; i < 4; ++i)
                #pragma unroll
                for (int j = 0; j < 4; ++j)
                    acc[i][j] = fmaf(a[i], b[j], acc[i][j]);
        }
        __syncthreads();
    }
    #pragma unroll
    for (int i = 0; i < 4; ++i) {
        const int m = bm + ty*4 + i;
        const float sm = sqq[m];
        float4 o;
        float v0 = sm + sqk[bn+tx*4+0] - 2.0f*acc[i][0];
        float v1 = sm + sqk[bn+tx*4+1] - 2.0f*acc[i][1];
        float v2 = sm + sqk[bn+tx*4+2] - 2.0f*acc[i][2];
        float v3 = sm + sqk[bn+tx*4+3] - 2.0f*acc[i][3];
        o.x = sqrtf(fmaxf(v0, 0.0f) + 1e-10f);
        o.y = sqrtf(fmaxf(v1, 0.0f) + 1e-10f);
        o.z = sqrtf(fmaxf(v2, 0.0f) + 1e-10f);
        o.w = sqrtf(fmaxf(v3, 0.0f) + 1e-10f);
        *(float4*)(Dm + (size_t)m * NN + bn + tx*4) = o;
    }
}

// ---------------------------------------------------------------------------
// Per-row order stats via radix bisection on float bits.
// ---------------------------------------------------------------------------
__device__ unsigned radix_kth_smallest(const unsigned* s, int lane, int K)
{
    unsigned lo = 0u, hi = 0xFFFFFFFFu;
    while (lo < hi) {
        unsigned mid = lo + ((hi - lo) >> 1);
        int c = 0;
        #pragma unroll 8
        for (int i = 0; i < 64; ++i) c += (s[i*64 + lane] <= mid) ? 1 : 0;
        for (int off = 32; off; off >>= 1) c += __shfl_xor(c, off);
        if (c >= K) hi = mid; else lo = mid + 1;
    }
    return lo;
}

__global__ __launch_bounds__(64) void select_kernel(
    const float* __restrict__ Dm, float* __restrict__ mdp, float* __restrict__ kth)
{
    __shared__ unsigned s[NN];
    const int row = blockIdx.x;
    const int lane = threadIdx.x;
    const float* src = Dm + (size_t)row * NN;
    for (int c = 0; c < 16; ++c) {
        const int base = c*256 + lane*4;
        float4 v = *(const float4*)(src + base);
        s[base+0] = __float_as_uint(v.x);
        s[base+1] = __float_as_uint(v.y);
        s[base+2] = __float_as_uint(v.z);
        s[base+3] = __float_as_uint(v.w);
    }
    __syncthreads();
    unsigned v11 = radix_kth_smallest(s, lane, 11);  // sort(d)[10]
    unsigned v30 = radix_kth_smallest(s, lane, 30);  // sort(d)[29]
    if (lane == 0) {
        float md = __uint_as_float(v11) + 1e-10f;
        float t  = __uint_as_float(v30) / md;
        mdp[row] = md;
        kth[row] = expf(-(t*t));   // same expr as aff_kernel -> identical rounding
    }
}

// ---------------------------------------------------------------------------
// Affinity transform in place + prune + diagonal (after prune, as reference).
// ---------------------------------------------------------------------------
__global__ __launch_bounds__(256) void aff_kernel(
    float* __restrict__ Dm, const float* __restrict__ mdp, const float* __restrict__ kthv)
{
    const size_t idx4 = ((size_t)blockIdx.x * 256 + threadIdx.x) * 4;
    const int i = (int)(idx4 >> 12);
    const int j = (int)(idx4 & 4095);
    const float m = mdp[i];
    const float kt = kthv[i];
    float4 v = *(float4*)(Dm + idx4);
    float t0 = v.x / m, t1 = v.y / m, t2 = v.z / m, t3 = v.w / m;
    float a0 = expf(-(t0*t0)), a1 = expf(-(t1*t1)), a2 = expf(-(t2*t2)), a3 = expf(-(t3*t3));
    a0 = (a0 >= kt) ? a0 : 0.0f;
    a1 = (a1 >= kt) ? a1 : 0.0f;
    a2 = (a2 >= kt) ? a2 : 0.0f;
    a3 = (a3 >= kt) ? a3 : 0.0f;
    if (j+0 == i) a0 = 1.0f;
    if (j+1 == i) a1 = 1.0f;
    if (j+2 == i) a2 = 1.0f;
    if (j+3 == i) a3 = 1.0f;
    v.x = a0; v.y = a1; v.z = a2; v.w = a3;
    *(float4*)(Dm + idx4) = v;
}

// ---------------------------------------------------------------------------
// In-place symmetrize A := A + A^T via 64x64 tile pairs.
// ---------------------------------------------------------------------------
__global__ __launch_bounds__(256) void sym_kernel(float* __restrict__ Dm)
{
    int rem = blockIdx.x;
    int bi = 0;
    while (rem >= 64 - bi) { rem -= 64 - bi; ++bi; }
    const int bj = bi + rem;

    __shared__ float T1[64][65];
    __shared__ float T2[64][65];
    const int t = threadIdx.x;
    const int lr = t >> 4;
    const int lc4 = (t & 15) * 4;

    #pragma unroll
    for (int rr = 0; rr < 4; ++rr) {
        const int r = rr*16 + lr;
        float4 v1 = *(const float4*)(Dm + (size_t)(bi*64 + r) * NN + bj*64 + lc4);
        T1[r][lc4+0]=v1.x; T1[r][lc4+1]=v1.y; T1[r][lc4+2]=v1.z; T1[r][lc4+3]=v1.w;
        float4 v2 = *(const float4*)(Dm + (size_t)(bj*64 + r) * NN + bi*64 + lc4);
        T2[r][lc4+0]=v2.x; T2[r][lc4+1]=v2.y; T2[r][lc4+2]=v2.z; T2[r][lc4+3]=v2.w;
    }
    __syncthreads();
    #pragma unroll
    for (int rr = 0; rr < 4; ++rr) {
        const int r = rr*16 + lr;
        float4 o1;
        o1.x = T1[r][lc4+0] + T2[lc4+0][r];
        o1.y = T1[r][lc4+1] + T2[lc4+1][r];
        o1.z = T1[r][lc4+2] + T2[lc4+2][r];
        o1.w = T1[r][lc4+3] + T2[lc4+3][r];
        *(float4*)(Dm + (size_t)(bi*64 + r) * NN + bj*64 + lc4) = o1;
        if (bi != bj) {
            float4 o2;
            o2.x = T2[r][lc4+0] + T1[lc4+0][r];
            o2.y = T2[r][lc4+1] + T1[lc4+1][r];
            o2.z = T2[r][lc4+2] + T1[lc4+2][r];
            o2.w = T2[r][lc4+3] + T1[lc4+3][r];
            *(float4*)(Dm + (size_t)(bj*64 + r) * NN + bi*64 + lc4) = o2;
        }
    }
}

// ---------------------------------------------------------------------------
__global__ __launch_bounds__(64) void zero_ovf_kernel(int* __restrict__ ovf_cnt)
{
    if (threadIdx.x == 0) *ovf_cnt = 0;
}

// ---------------------------------------------------------------------------
// Softmax row stats + sparse extraction. P[i][j] = ci + v_ij (v=0 off-support).
// Rows padded to a multiple of 8 with (col=0,val=0) so spmm can run fixed
// unroll-8 chunks. Entries beyond CAP spill to overflow list (exactness).
// ---------------------------------------------------------------------------
__global__ __launch_bounds__(256) void stats_extract_kernel(
    const float* __restrict__ A, float* __restrict__ cvec, int* __restrict__ nnz,
    int* __restrict__ cols, float* __restrict__ vals,
    int* __restrict__ ovf_cnt, int* __restrict__ ovf_row,
    int* __restrict__ ovf_col, float* __restrict__ ovf_val)
{
    __shared__ float srow[NN];
    __shared__ float red[8];
    __shared__ int cnt;
    const int row = blockIdx.x, t = threadIdx.x;
    const int lane = t & 63, wid = t >> 6;
    const float* src = A + (size_t)row * NN;

    float mx = -1e30f;
    #pragma unroll
    for (int c = 0; c < 4; ++c) {
        const int base = c*1024 + t*4;
        float4 v = *(const float4*)(src + base);
        *(float4*)&srow[base] = v;
        mx = fmaxf(mx, fmaxf(fmaxf(v.x, v.y), fmaxf(v.z, v.w)));
    }
    for (int off = 32; off; off >>= 1) mx = fmaxf(mx, __shfl_xor(mx, off));
    if (lane == 0) red[wid] = mx;
    __syncthreads();
    mx = fmaxf(fmaxf(red[0], red[1]), fmaxf(red[2], red[3]));

    float sum = 0.0f;
    #pragma unroll
    for (int c = 0; c < 4; ++c) {
        const int base = c*1024 + t*4;
        float4 v = *(float4*)&srow[base];
        sum += expf(v.x-mx) + expf(v.y-mx) + expf(v.z-mx) + expf(v.w-mx);
    }
    for (int off = 32; off; off >>= 1) sum += __shfl_xor(sum, off);
    if (lane == 0) red[4 + wid] = sum;
    if (t == 0) cnt = 0;
    __syncthreads();
    sum = red[4] + red[5] + red[6] + red[7];
    const float ci = expf(-mx) / sum;
    if (t == 0) cvec[row] = ci;

    for (int c = 0; c < 16; ++c) {
        const int j = c*256 + t;
        const float a = srow[j];
        if (a != 0.0f) {
            const float v = expf(a - mx)/sum - ci;
            int p = atomicAdd(&cnt, 1);
            if (p < CAP) {
                cols[(size_t)row*CAP + p] = j;
                vals[(size_t)row*CAP + p] = v;
            } else {
                int q = atomicAdd(ovf_cnt, 1);
                if (q < OVF_CAP) {
                    ovf_row[q] = row;
                    ovf_col[q] = j;
                    ovf_val[q] = v;
                }
            }
        }
    }
    __syncthreads();
    if (t == 0) {
        const int c2 = min(cnt, CAP);
        const int e2 = min((c2 + 7) & ~7, CAP);   // pad to multiple of 8
        for (int p = c2; p < e2; ++p) {
            cols[(size_t)row*CAP + p] = 0;
            vals[(size_t)row*CAP + p] = 0.0f;     // weight-0 gather of row 0: no-op
        }
        nnz[row] = e2 == c2 ? c2 : e2;            // padded count (multiple of 8)
    }
}

// ---------------------------------------------------------------------------
// Column sums of Y [NN][DIN], two-stage deterministic.
// ---------------------------------------------------------------------------
__global__ __launch_bounds__(256) void colsum_partial_kernel(
    const float* __restrict__ Y, float* __restrict__ part)
{
    const int cc = blockIdx.y * 256 + threadIdx.x;
    const int r0 = blockIdx.x * 128;
    float s = 0.0f;
    for (int r = 0; r < 128; ++r) s += Y[(size_t)(r0 + r) * DIN + cc];
    part[(size_t)blockIdx.x * DIN + cc] = s;
}

__global__ __launch_bounds__(256) void colsum_final_kernel(
    const float* __restrict__ part, float* __restrict__ colsum)
{
    const int cc = blockIdx.x * 256 + threadIdx.x;
    float s = 0.0f;
    #pragma unroll
    for (int r = 0; r < 32; ++r) s += part[(size_t)r * DIN + cc];
    colsum[cc] = s;
}

// ---------------------------------------------------------------------------
// Panel-blocked sparse+rank-1 application with register-staged metadata:
//   Yout[i][panel] = c_i*colsum[panel] + sum_nz v * Y[j][panel]
// One wave per (row, panel). Metadata loaded 64-at-a-time into lane registers
// (2 coalesced loads), broadcast via __shfl -> gather loop has NO memory
// dependence; unroll-8 keeps 8 independent gathers in flight per wave.
// mode 0: write; mode 1: write 0.25x; mode 2: += 0.25x
// ---------------------------------------------------------------------------
__global__ __launch_bounds__(256) void spmm_kernel(
    const float* __restrict__ Y, const float* __restrict__ colsum,
    const float* __restrict__ cvec, const int* __restrict__ nnz,
    const int* __restrict__ cols, const float* __restrict__ vals,
    float* __restrict__ Yout, int mode)
{
    const int wave = threadIdx.x >> 6, lane = threadIdx.x & 63;
    const int row = blockIdx.x * 4 + wave;
    const int c = blockIdx.y * PW + lane * 2;

    const int n = nnz[row];               // multiple of 8 (padded)
    const float ci = cvec[row];
    const int*   rc = cols + (size_t)row * CAP;
    const float* rv = vals + (size_t)row * CAP;

    const float2 s = *(const float2*)(colsum + c);
    float ax = ci * s.x, ay = ci * s.y;

    for (int base = 0; base < n; base += 64) {
        const int rem = min(64, n - base);   // multiple of 8
        int jl = 0; float vl = 0.0f;
        if (lane < rem) { jl = rc[base + lane]; vl = rv[base + lane]; }
        for (int e = 0; e < rem; e += 8) {
            #pragma unroll
            for (int u = 0; u < 8; ++u) {
                const int j = __shfl(jl, e + u);
                const float v = __shfl(vl, e + u);
                const float2 y = *(const float2*)(Y + (size_t)j * DIN + c);
                ax = fmaf(v, y.x, ax);
                ay = fmaf(v, y.y, ay);
            }
        }
    }

    float* dst = Yout + (size_t)row * DIN + c;
    float2 o;
    if (mode == 0)      { o.x = ax;       o.y = ay; }
    else if (mode == 1) { o.x = 0.25f*ax; o.y = 0.25f*ay; }
    else {
        const float2 p = *(const float2*)dst;
        o.x = p.x + 0.25f*ax; o.y = p.y + 0.25f*ay;
    }
    *(float2*)dst = o;
}

// ---------------------------------------------------------------------------
// Apply spilled overflow entries: Yout[i][:] += scale * v * Y[j][:].
// Expected count ~0; exactness guarantee for hub rows with nnz > CAP.
// ---------------------------------------------------------------------------
__global__ __launch_bounds__(256) void spmm_fixup_kernel(
    const float* __restrict__ Y, const int* __restrict__ ovf_cnt,
    const int* __restrict__ ovf_row, const int* __restrict__ ovf_col,
    const float* __restrict__ ovf_val, float* __restrict__ Yout, float scale)
{
    const int cnt = min(*ovf_cnt, OVF_CAP);
    const int t = threadIdx.x;
    for (int e = blockIdx.x; e < cnt; e += gridDim.x) {
        const int i = ovf_row[e], j = ovf_col[e];
        const float v = ovf_val[e] * scale;
        const float* yr = Y + (size_t)j * DIN;
        float* dst = Yout + (size_t)i * DIN;
        #pragma unroll
        for (int c = t*4; c < DIN; c += 1024) {
            atomicAdd(dst + c + 0, v * yr[c + 0]);
            atomicAdd(dst + c + 1, v * yr[c + 1]);
            atomicAdd(dst + c + 2, v * yr[c + 2]);
            atomicAdd(dst + c + 3, v * yr[c + 3]);
        }
    }
}

// ---------------------------------------------------------------------------
extern "C" void kernel_launch(void* const* d_in, const int* in_sizes, int n_in,
                              void* d_out, int out_size, void* d_ws, size_t ws_size,
                              hipStream_t stream)
{
    const float* X  = (const float*)d_in[0];
    const float* Wq = (const float*)d_in[1];
    const float* bq = (const float*)d_in[2];
    const float* Wk = (const float*)d_in[3];
    const float* bk = (const float*)d_in[4];
    float* out = (float*)d_out;

    float* ws   = (float*)d_ws;
    float* qbuf = ws;                                   //  NN*HID
    float* kbuf = qbuf + (size_t)NN*HID;                //  NN*HID
    float* A    = kbuf + (size_t)NN*HID;                //  NN*NN (64MB)
    float* Y1   = A;                                    //  overlays A (A dead after extract)
    float* Y2   = A + (size_t)NN*DIN;                   //  overlays A upper half
    float* valsA= A + (size_t)NN*NN;                    //  NN*CAP
    int*   colsA= (int*)(valsA + (size_t)NN*CAP);       //  NN*CAP
    float* part = (float*)(colsA + (size_t)NN*CAP);     //  32*DIN
    float* colsum = part + 32*DIN;                      //  DIN
    float* sqq  = colsum + DIN;
    float* sqk  = sqq + NN;
    float* mdp  = sqk + NN;
    float* kth  = mdp + NN;
    float* cvec = kth + NN;
    int*   nnz  = (int*)(cvec + NN);
    int*   ovf_cnt = nnz + NN;
    int*   ovf_row = ovf_cnt + 16;
    int*   ovf_col = ovf_row + OVF_CAP;
    float* ovf_val = (float*)(ovf_col + OVF_CAP);

    for (int h = 0; h < NHEADS; ++h) {
        proj_kernel<<<dim3(NN/64, HID/64, 2), 256, 0, stream>>>(X, Wq, bq, Wk, bk, qbuf, kbuf, h);
        rownorm_kernel<<<dim3(NN, 2), 64, 0, stream>>>(qbuf, kbuf, sqq, sqk);
        dist_kernel<<<dim3(NN/64, NN/64), 256, 0, stream>>>(qbuf, kbuf, sqq, sqk, A);
        select_kernel<<<dim3(NN), 64, 0, stream>>>(A, mdp, kth);
        aff_kernel<<<dim3(NN*NN/1024), 256, 0, stream>>>(A, mdp, kth);
        sym_kernel<<<dim3(2080), 256, 0, stream>>>(A);
        zero_ovf_kernel<<<dim3(1), 64, 0, stream>>>(ovf_cnt);
        stats_extract_kernel<<<dim3(NN), 256, 0, stream>>>(A, cvec, nnz, colsA, valsA,
                                                           ovf_cnt, ovf_row, ovf_col, ovf_val);

        const float* src = X;
        for (int tpow = 1; tpow <= 6; ++tpow) {
            colsum_partial_kernel<<<dim3(32, DIN/256), 256, 0, stream>>>(src, part);
            colsum_final_kernel<<<dim3(DIN/256), 256, 0, stream>>>(part, colsum);
            float* dst;
            int mode;
            if (tpow == 6)      { dst = out; mode = (h == 0) ? 1 : 2; }
            else if (tpow & 1)  { dst = Y1;  mode = 0; }
            else                { dst = Y2;  mode = 0; }
            spmm_kernel<<<dim3(NN/4, DIN/PW), 256, 0, stream>>>(src, colsum, cvec, nnz, colsA, valsA, dst, mode);
            spmm_fixup_kernel<<<dim3(64), 256, 0, stream>>>(src, ovf_cnt, ovf_row, ovf_col, ovf_val,
                                                            dst, (tpow == 6) ? 0.25f : 1.0f);
            src = dst;
        }
    }
}

// Round 6
// 7259.977 us; speedup vs baseline: 2.8396x; 1.0128x over previous
//
#include <hip/hip_runtime.h>
#include <hip/hip_bf16.h>
#include <math.h>

#define NN 4096
#define DIN 2048
#define HID 256
#define NHEADS 4
#define CAP 1024       // fast-path nnz per row; multiple of 8 (padding invariant)
#define OVF_CAP 131072 // spill capacity for rows exceeding CAP (exactness guarantee)
#define PW 128         // spmm panel width (floats): 4096*PW*4B = 2MB panel -> L2-resident

// ---------------------------------------------------------------------------
// Projection GEMM (NT) for ONE head: out[n][c] = sum_d X[n][d]*W[c][d] + b[c]
// ---------------------------------------------------------------------------
__global__ __launch_bounds__(256) void proj_kernel(
    const float* __restrict__ X, const float* __restrict__ Wq, const float* __restrict__ bq,
    const float* __restrict__ Wk, const float* __restrict__ bk,
    float* __restrict__ qbuf, float* __restrict__ kbuf, int h)
{
    const int isK = blockIdx.z;
    const float* W    = (isK ? Wk : Wq) + (size_t)h * HID * DIN;
    const float* bias = (isK ? bk : bq) + h * HID;
    float* out = isK ? kbuf : qbuf;

    const int bm = blockIdx.x * 64;
    const int bn = blockIdx.y * 64;
    const int t  = threadIdx.x;
    const int tx = t & 15, ty = t >> 4;
    const int lr = t >> 2, lk = (t & 3) * 4;

    __shared__ float As[16][68];
    __shared__ float Bs[16][68];
    float acc[4][4] = {};

    for (int k0 = 0; k0 < DIN; k0 += 16) {
        float4 av = *(const float4*)(X + (size_t)(bm + lr) * DIN + k0 + lk);
        float4 bv = *(const float4*)(W + (size_t)(bn + lr) * DIN + k0 + lk);
        As[lk+0][lr]=av.x; As[lk+1][lr]=av.y; As[lk+2][lr]=av.z; As[lk+3][lr]=av.w;
        Bs[lk+0][lr]=bv.x; Bs[lk+1][lr]=bv.y; Bs[lk+2][lr]=bv.z; Bs[lk+3][lr]=bv.w;
        __syncthreads();
        #pragma unroll
        for (int kk = 0; kk < 16; ++kk) {
            const float4 a4 = *(const float4*)&As[kk][ty*4];
            const float4 b4 = *(const float4*)&Bs[kk][tx*4];
            const float a[4] = {a4.x,a4.y,a4.z,a4.w};
            const float b[4] = {b4.x,b4.y,b4.z,b4.w};
            #pragma unroll
            for (int i = 0; i < 4; ++i)
                #pragma unroll
                for (int j = 0; j < 4; ++j)
                    acc[i][j] = fmaf(a[i], b[j], acc[i][j]);
        }
        __syncthreads();
    }
    #pragma unroll
    for (int i = 0; i < 4; ++i) {
        const int m = bm + ty*4 + i;
        float4 o;
        o.x = acc[i][0] + bias[bn+tx*4+0];
        o.y = acc[i][1] + bias[bn+tx*4+1];
        o.z = acc[i][2] + bias[bn+tx*4+2];
        o.w = acc[i][3] + bias[bn+tx*4+3];
        *(float4*)(out + (size_t)m * HID + bn + tx*4) = o;
    }
}

// ---------------------------------------------------------------------------
__global__ __launch_bounds__(64) void rownorm_kernel(
    const float* __restrict__ q, const float* __restrict__ k,
    float* __restrict__ sqq, float* __restrict__ sqk)
{
    const int row = blockIdx.x;
    const int lane = threadIdx.x;
    const float* src = (blockIdx.y ? k : q) + (size_t)row * HID;
    float4 v = *(const float4*)(src + lane * 4);
    float s = v.x*v.x + v.y*v.y + v.z*v.z + v.w*v.w;
    for (int off = 32; off; off >>= 1) s += __shfl_down(s, off);
    if (lane == 0) (blockIdx.y ? sqk : sqq)[row] = s;
}

// ---------------------------------------------------------------------------
// Gram GEMM (NT, K=HID) + distance epilogue.
// ---------------------------------------------------------------------------
__global__ __launch_bounds__(256) void dist_kernel(
    const float* __restrict__ q, const float* __restrict__ k,
    const float* __restrict__ sqq, const float* __restrict__ sqk,
    float* __restrict__ Dm)
{
    const int bm = blockIdx.x * 64;
    const int bn = blockIdx.y * 64;
    const int t  = threadIdx.x;
    const int tx = t & 15, ty = t >> 4;
    const int lr = t >> 2, lk = (t & 3) * 4;

    __shared__ float As[16][68];
    __shared__ float Bs[16][68];
    float acc[4][4] = {};

    for (int k0 = 0; k0 < HID; k0 += 16) {
        float4 av = *(const float4*)(q + (size_t)(bm + lr) * HID + k0 + lk);
        float4 bv = *(const float4*)(k + (size_t)(bn + lr) * HID + k0 + lk);
        As[lk+0][lr]=av.x; As[lk+1][lr]=av.y; As[lk+2][lr]=av.z; As[lk+3][lr]=av.w;
        Bs[lk+0][lr]=bv.x; Bs[lk+1][lr]=bv.y; Bs[lk+2][lr]=bv.z; Bs[lk+3][lr]=bv.w;
        __syncthreads();
        #pragma unroll
        for (int kk = 0; kk < 16; ++kk) {
            const float4 a4 = *(const float4*)&As[kk][ty*4];
            const float4 b4 = *(const float4*)&Bs[kk][tx*4];
            const float a[4] = {a4.x,a4.y,a4.z,a4.w};
            const float b[4] = {b4.x,b4.y,b4.z,b4.w};
            #pragma unroll
            for (int i = 0; i < 4; ++i)
                #pragma unroll
                for (int j = 0; j < 4; ++j)
                    acc[i][j] = fmaf(a[i], b[j], acc[i][j]);
        }
        __syncthreads();
    }
    #pragma unroll
    for (int i = 0; i < 4; ++i) {
        const int m = bm + ty*4 + i;
        const float sm = sqq[m];
        float4 o;
        float v0 = sm + sqk[bn+tx*4+0] - 2.0f*acc[i][0];
        float v1 = sm + sqk[bn+tx*4+1] - 2.0f*acc[i][1];
        float v2 = sm + sqk[bn+tx*4+2] - 2.0f*acc[i][2];
        float v3 = sm + sqk[bn+tx*4+3] - 2.0f*acc[i][3];
        o.x = sqrtf(fmaxf(v0, 0.0f) + 1e-10f);
        o.y = sqrtf(fmaxf(v1, 0.0f) + 1e-10f);
        o.z = sqrtf(fmaxf(v2, 0.0f) + 1e-10f);
        o.w = sqrtf(fmaxf(v3, 0.0f) + 1e-10f);
        *(float4*)(Dm + (size_t)m * NN + bn + tx*4) = o;
    }
}

// ---------------------------------------------------------------------------
// Per-row order stats via radix bisection on float bits.
// ---------------------------------------------------------------------------
__device__ unsigned radix_kth_smallest(const unsigned* s, int lane, int K)
{
    unsigned lo = 0u, hi = 0xFFFFFFFFu;
    while (lo < hi) {
        unsigned mid = lo + ((hi - lo) >> 1);
        int c = 0;
        #pragma unroll 8
        for (int i = 0; i < 64; ++i) c += (s[i*64 + lane] <= mid) ? 1 : 0;
        for (int off = 32; off; off >>= 1) c += __shfl_xor(c, off);
        if (c >= K) hi = mid; else lo = mid + 1;
    }
    return lo;
}

__global__ __launch_bounds__(64) void select_kernel(
    const float* __restrict__ Dm, float* __restrict__ mdp, float* __restrict__ kth)
{
    __shared__ unsigned s[NN];
    const int row = blockIdx.x;
    const int lane = threadIdx.x;
    const float* src = Dm + (size_t)row * NN;
    for (int c = 0; c < 16; ++c) {
        const int base = c*256 + lane*4;
        float4 v = *(const float4*)(src + base);
        s[base+0] = __float_as_uint(v.x);
        s[base+1] = __float_as_uint(v.y);
        s[base+2] = __float_as_uint(v.z);
        s[base+3] = __float_as_uint(v.w);
    }
    __syncthreads();
    unsigned v11 = radix_kth_smallest(s, lane, 11);  // sort(d)[10]
    unsigned v30 = radix_kth_smallest(s, lane, 30);  // sort(d)[29]
    if (lane == 0) {
        float md = __uint_as_float(v11) + 1e-10f;
        float t  = __uint_as_float(v30) / md;
        mdp[row] = md;
        kth[row] = expf(-(t*t));   // same expr as aff_kernel -> identical rounding
    }
}

// ---------------------------------------------------------------------------
// Affinity transform in place + prune + diagonal (after prune, as reference).
// ---------------------------------------------------------------------------
__global__ __launch_bounds__(256) void aff_kernel(
    float* __restrict__ Dm, const float* __restrict__ mdp, const float* __restrict__ kthv)
{
    const size_t idx4 = ((size_t)blockIdx.x * 256 + threadIdx.x) * 4;
    const int i = (int)(idx4 >> 12);
    const int j = (int)(idx4 & 4095);
    const float m = mdp[i];
    const float kt = kthv[i];
    float4 v = *(float4*)(Dm + idx4);
    float t0 = v.x / m, t1 = v.y / m, t2 = v.z / m, t3 = v.w / m;
    float a0 = expf(-(t0*t0)), a1 = expf(-(t1*t1)), a2 = expf(-(t2*t2)), a3 = expf(-(t3*t3));
    a0 = (a0 >= kt) ? a0 : 0.0f;
    a1 = (a1 >= kt) ? a1 : 0.0f;
    a2 = (a2 >= kt) ? a2 : 0.0f;
    a3 = (a3 >= kt) ? a3 : 0.0f;
    if (j+0 == i) a0 = 1.0f;
    if (j+1 == i) a1 = 1.0f;
    if (j+2 == i) a2 = 1.0f;
    if (j+3 == i) a3 = 1.0f;
    v.x = a0; v.y = a1; v.z = a2; v.w = a3;
    *(float4*)(Dm + idx4) = v;
}

// ---------------------------------------------------------------------------
// In-place symmetrize A := A + A^T via 64x64 tile pairs.
// ---------------------------------------------------------------------------
__global__ __launch_bounds__(256) void sym_kernel(float* __restrict__ Dm)
{
    int rem = blockIdx.x;
    int bi = 0;
    while (rem >= 64 - bi) { rem -= 64 - bi; ++bi; }
    const int bj = bi + rem;

    __shared__ float T1[64][65];
    __shared__ float T2[64][65];
    const int t = threadIdx.x;
    const int lr = t >> 4;
    const int lc4 = (t & 15) * 4;

    #pragma unroll
    for (int rr = 0; rr < 4; ++rr) {
        const int r = rr*16 + lr;
        float4 v1 = *(const float4*)(Dm + (size_t)(bi*64 + r) * NN + bj*64 + lc4);
        T1[r][lc4+0]=v1.x; T1[r][lc4+1]=v1.y; T1[r][lc4+2]=v1.z; T1[r][lc4+3]=v1.w;
        float4 v2 = *(const float4*)(Dm + (size_t)(bj*64 + r) * NN + bi*64 + lc4);
        T2[r][lc4+0]=v2.x; T2[r][lc4+1]=v2.y; T2[r][lc4+2]=v2.z; T2[r][lc4+3]=v2.w;
    }
    __syncthreads();
    #pragma unroll
    for (int rr = 0; rr < 4; ++rr) {
        const int r = rr*16 + lr;
        float4 o1;
        o1.x = T1[r][lc4+0] + T2[lc4+0][r];
        o1.y = T1[r][lc4+1] + T2[lc4+1][r];
        o1.z = T1[r][lc4+2] + T2[lc4+2][r];
        o1.w = T1[r][lc4+3] + T2[lc4+3][r];
        *(float4*)(Dm + (size_t)(bi*64 + r) * NN + bj*64 + lc4) = o1;
        if (bi != bj) {
            float4 o2;
            o2.x = T2[r][lc4+0] + T1[lc4+0][r];
            o2.y = T2[r][lc4+1] + T1[lc4+1][r];
            o2.z = T2[r][lc4+2] + T1[lc4+2][r];
            o2.w = T2[r][lc4+3] + T1[lc4+3][r];
            *(float4*)(Dm + (size_t)(bj*64 + r) * NN + bi*64 + lc4) = o2;
        }
    }
}

// ---------------------------------------------------------------------------
__global__ __launch_bounds__(64) void zero_ovf_kernel(int* __restrict__ ovf_cnt)
{
    if (threadIdx.x == 0) *ovf_cnt = 0;
}

// ---------------------------------------------------------------------------
// Softmax row stats + sparse extraction. P[i][j] = ci + v_ij (v=0 off-support).
// Rows padded to a multiple of 8 with (col=0,val=0) so spmm can run fixed
// unroll-8 chunks. Entries beyond CAP spill to overflow list (exactness).
// ---------------------------------------------------------------------------
__global__ __launch_bounds__(256) void stats_extract_kernel(
    const float* __restrict__ A, float* __restrict__ cvec, int* __restrict__ nnz,
    int* __restrict__ cols, float* __restrict__ vals,
    int* __restrict__ ovf_cnt, int* __restrict__ ovf_row,
    int* __restrict__ ovf_col, float* __restrict__ ovf_val)
{
    __shared__ float srow[NN];
    __shared__ float red[8];
    __shared__ int cnt;
    const int row = blockIdx.x, t = threadIdx.x;
    const int lane = t & 63, wid = t >> 6;
    const float* src = A + (size_t)row * NN;

    float mx = -1e30f;
    #pragma unroll
    for (int c = 0; c < 4; ++c) {
        const int base = c*1024 + t*4;
        float4 v = *(const float4*)(src + base);
        *(float4*)&srow[base] = v;
        mx = fmaxf(mx, fmaxf(fmaxf(v.x, v.y), fmaxf(v.z, v.w)));
    }
    for (int off = 32; off; off >>= 1) mx = fmaxf(mx, __shfl_xor(mx, off));
    if (lane == 0) red[wid] = mx;
    __syncthreads();
    mx = fmaxf(fmaxf(red[0], red[1]), fmaxf(red[2], red[3]));

    float sum = 0.0f;
    #pragma unroll
    for (int c = 0; c < 4; ++c) {
        const int base = c*1024 + t*4;
        float4 v = *(float4*)&srow[base];
        sum += expf(v.x-mx) + expf(v.y-mx) + expf(v.z-mx) + expf(v.w-mx);
    }
    for (int off = 32; off; off >>= 1) sum += __shfl_xor(sum, off);
    if (lane == 0) red[4 + wid] = sum;
    if (t == 0) cnt = 0;
    __syncthreads();
    sum = red[4] + red[5] + red[6] + red[7];
    const float ci = expf(-mx) / sum;
    if (t == 0) cvec[row] = ci;

    for (int c = 0; c < 16; ++c) {
        const int j = c*256 + t;
        const float a = srow[j];
        if (a != 0.0f) {
            const float v = expf(a - mx)/sum - ci;
            int p = atomicAdd(&cnt, 1);
            if (p < CAP) {
                cols[(size_t)row*CAP + p] = j;
                vals[(size_t)row*CAP + p] = v;
            } else {
                int q = atomicAdd(ovf_cnt, 1);
                if (q < OVF_CAP) {
                    ovf_row[q] = row;
                    ovf_col[q] = j;
                    ovf_val[q] = v;
                }
            }
        }
    }
    __syncthreads();
    if (t == 0) {
        const int c2 = min(cnt, CAP);
        const int e2 = min((c2 + 7) & ~7, CAP);   // pad to multiple of 8
        for (int p = c2; p < e2; ++p) {
            cols[(size_t)row*CAP + p] = 0;
            vals[(size_t)row*CAP + p] = 0.0f;     // weight-0 gather of row 0: no-op
        }
        nnz[row] = e2 == c2 ? c2 : e2;            // padded count (multiple of 8)
    }
}

// ---------------------------------------------------------------------------
// Column sums of Y [NN][DIN], two-stage deterministic.
// ---------------------------------------------------------------------------
__global__ __launch_bounds__(256) void colsum_partial_kernel(
    const float* __restrict__ Y, float* __restrict__ part)
{
    const int cc = blockIdx.y * 256 + threadIdx.x;
    const int r0 = blockIdx.x * 128;
    float s = 0.0f;
    for (int r = 0; r < 128; ++r) s += Y[(size_t)(r0 + r) * DIN + cc];
    part[(size_t)blockIdx.x * DIN + cc] = s;
}

__global__ __launch_bounds__(256) void colsum_final_kernel(
    const float* __restrict__ part, float* __restrict__ colsum)
{
    const int cc = blockIdx.x * 256 + threadIdx.x;
    float s = 0.0f;
    #pragma unroll
    for (int r = 0; r < 32; ++r) s += part[(size_t)r * DIN + cc];
    colsum[cc] = s;
}

// ---------------------------------------------------------------------------
// Panel-blocked sparse+rank-1 application, scalar-pipe metadata + deep MLP:
//   Yout[i][panel] = c_i*colsum[panel] + sum_nz v * Y[j][panel]
// One wave per (row, panel). `row` is pinned wave-uniform via readfirstlane so
// cols[]/vals[] indexing compiles to s_load (SGPR broadcast, no ds_bpermute).
// Each 8-entry chunk loads into independent temporaries BEFORE the FMAs ->
// 8 outstanding global_load_dwordx2 per wave (vmcnt staircase, not vmcnt(0)).
// mode 0: write; mode 1: write 0.25x; mode 2: += 0.25x
// ---------------------------------------------------------------------------
__global__ __launch_bounds__(256) void spmm_kernel(
    const float* __restrict__ Y, const float* __restrict__ colsum,
    const float* __restrict__ cvec, const int* __restrict__ nnz,
    const int* __restrict__ cols, const float* __restrict__ vals,
    float* __restrict__ Yout, int mode)
{
    const int wave = threadIdx.x >> 6, lane = threadIdx.x & 63;
    const int row = __builtin_amdgcn_readfirstlane(blockIdx.x * 4 + wave);
    const int c = blockIdx.y * PW + lane * 2;

    const int n = nnz[row];               // multiple of 8 (padded), scalar
    const float ci = cvec[row];
    const int*   rc = cols + (size_t)row * CAP;   // SGPR base -> s_load
    const float* rv = vals + (size_t)row * CAP;

    const float2 s = *(const float2*)(colsum + c);
    float ax = ci * s.x, ay = ci * s.y;

    for (int base = 0; base < n; base += 8) {
        float2 y[8];
        #pragma unroll
        for (int u = 0; u < 8; ++u) {
            const int j = rc[base + u];            // scalar load, uniform
            y[u] = *(const float2*)(Y + (size_t)j * DIN + c);
        }
        #pragma unroll
        for (int u = 0; u < 8; ++u) {
            const float v = rv[base + u];          // scalar load, uniform
            ax = fmaf(v, y[u].x, ax);
            ay = fmaf(v, y[u].y, ay);
        }
    }

    float* dst = Yout + (size_t)row * DIN + c;
    float2 o;
    if (mode == 0)      { o.x = ax;       o.y = ay; }
    else if (mode == 1) { o.x = 0.25f*ax; o.y = 0.25f*ay; }
    else {
        const float2 p = *(const float2*)dst;
        o.x = p.x + 0.25f*ax; o.y = p.y + 0.25f*ay;
    }
    *(float2*)dst = o;
}

// ---------------------------------------------------------------------------
// Apply spilled overflow entries: Yout[i][:] += scale * v * Y[j][:].
// Expected count ~0; exactness guarantee for hub rows with nnz > CAP.
// ---------------------------------------------------------------------------
__global__ __launch_bounds__(256) void spmm_fixup_kernel(
    const float* __restrict__ Y, const int* __restrict__ ovf_cnt,
    const int* __restrict__ ovf_row, const int* __restrict__ ovf_col,
    const float* __restrict__ ovf_val, float* __restrict__ Yout, float scale)
{
    const int cnt = min(*ovf_cnt, OVF_CAP);
    const int t = threadIdx.x;
    for (int e = blockIdx.x; e < cnt; e += gridDim.x) {
        const int i = ovf_row[e], j = ovf_col[e];
        const float v = ovf_val[e] * scale;
        const float* yr = Y + (size_t)j * DIN;
        float* dst = Yout + (size_t)i * DIN;
        #pragma unroll
        for (int c = t*4; c < DIN; c += 1024) {
            atomicAdd(dst + c + 0, v * yr[c + 0]);
            atomicAdd(dst + c + 1, v * yr[c + 1]);
            atomicAdd(dst + c + 2, v * yr[c + 2]);
            atomicAdd(dst + c + 3, v * yr[c + 3]);
        }
    }
}

// ---------------------------------------------------------------------------
extern "C" void kernel_launch(void* const* d_in, const int* in_sizes, int n_in,
                              void* d_out, int out_size, void* d_ws, size_t ws_size,
                              hipStream_t stream)
{
    const float* X  = (const float*)d_in[0];
    const float* Wq = (const float*)d_in[1];
    const float* bq = (const float*)d_in[2];
    const float* Wk = (const float*)d_in[3];
    const float* bk = (const float*)d_in[4];
    float* out = (float*)d_out;

    float* ws   = (float*)d_ws;
    float* qbuf = ws;                                   //  NN*HID
    float* kbuf = qbuf + (size_t)NN*HID;                //  NN*HID
    float* A    = kbuf + (size_t)NN*HID;                //  NN*NN (64MB)
    float* Y1   = A;                                    //  overlays A (A dead after extract)
    float* Y2   = A + (size_t)NN*DIN;                   //  overlays A upper half
    float* valsA= A + (size_t)NN*NN;                    //  NN*CAP
    int*   colsA= (int*)(valsA + (size_t)NN*CAP);       //  NN*CAP
    float* part = (float*)(colsA + (size_t)NN*CAP);     //  32*DIN
    float* colsum = part + 32*DIN;                      //  DIN
    float* sqq  = colsum + DIN;
    float* sqk  = sqq + NN;
    float* mdp  = sqk + NN;
    float* kth  = mdp + NN;
    float* cvec = kth + NN;
    int*   nnz  = (int*)(cvec + NN);
    int*   ovf_cnt = nnz + NN;
    int*   ovf_row = ovf_cnt + 16;
    int*   ovf_col = ovf_row + OVF_CAP;
    float* ovf_val = (float*)(ovf_col + OVF_CAP);

    for (int h = 0; h < NHEADS; ++h) {
        proj_kernel<<<dim3(NN/64, HID/64, 2), 256, 0, stream>>>(X, Wq, bq, Wk, bk, qbuf, kbuf, h);
        rownorm_kernel<<<dim3(NN, 2), 64, 0, stream>>>(qbuf, kbuf, sqq, sqk);
        dist_kernel<<<dim3(NN/64, NN/64), 256, 0, stream>>>(qbuf, kbuf, sqq, sqk, A);
        select_kernel<<<dim3(NN), 64, 0, stream>>>(A, mdp, kth);
        aff_kernel<<<dim3(NN*NN/1024), 256, 0, stream>>>(A, mdp, kth);
        sym_kernel<<<dim3(2080), 256, 0, stream>>>(A);
        zero_ovf_kernel<<<dim3(1), 64, 0, stream>>>(ovf_cnt);
        stats_extract_kernel<<<dim3(NN), 256, 0, stream>>>(A, cvec, nnz, colsA, valsA,
                                                           ovf_cnt, ovf_row, ovf_col, ovf_val);

        const float* src = X;
        for (int tpow = 1; tpow <= 6; ++tpow) {
            colsum_partial_kernel<<<dim3(32, DIN/256), 256, 0, stream>>>(src, part);
            colsum_final_kernel<<<dim3(DIN/256), 256, 0, stream>>>(part, colsum);
            float* dst;
            int mode;
            if (tpow == 6)      { dst = out; mode = (h == 0) ? 1 : 2; }
            else if (tpow & 1)  { dst = Y1;  mode = 0; }
            else                { dst = Y2;  mode = 0; }
            spmm_kernel<<<dim3(NN/4, DIN/PW), 256, 0, stream>>>(src, colsum, cvec, nnz, colsA, valsA, dst, mode);
            spmm_fixup_kernel<<<dim3(64), 256, 0, stream>>>(src, ovf_cnt, ovf_row, ovf_col, ovf_val,
                                                            dst, (tpow == 6) ? 0.25f : 1.0f);
            src = dst;
        }
    }
}